// Round 1
// baseline (995.959 us; speedup 1.0000x reference)
//
#include <hip/hip_runtime.h>

#define BATCH 16384
#define LAYERS 63

typedef float f4v __attribute__((ext_vector_type(4)));

__device__ __forceinline__ float fast_tanh(float v) {
    float e = __expf(2.f * v);
    return 1.f - 2.f / (e + 1.f);
}

__device__ __forceinline__ float softplus_f(float v) {
    return fmaxf(v, 0.f) + __logf(1.f + __expf(-fabsf(v)));
}

// One-time transpose of weights so MLP kernel can stage LDS with flat coalesced
// copies and read B-operand fragments as conflict-free float4 rows.
// W1T/W2T: [l][d][j] (64x64), W3T: [l][h][o] padded o->24.
__global__ __launch_bounds__(256) void transpose_w(
    const float* __restrict__ W1, const float* __restrict__ W2, const float* __restrict__ W3,
    float* __restrict__ W1T, float* __restrict__ W2T, float* __restrict__ W3T)
{
    const int l = blockIdx.x, tid = threadIdx.x;
    const float* w1 = W1 + l * 4096; float* t1 = W1T + l * 4096;
    const float* w2 = W2 + l * 4096; float* t2 = W2T + l * 4096;
    const float* w3 = W3 + l * 1472; float* t3 = W3T + l * 1536;
    for (int e = tid; e < 4096; e += 256) { int d = e >> 6, j = e & 63; t1[e] = w1[j * 64 + d]; }
    for (int e = tid; e < 4096; e += 256) { int d = e >> 6, j = e & 63; t2[e] = w2[j * 64 + d]; }
    for (int e = tid; e < 1536; e += 256) { int d = e / 24, o = e - d * 24; t3[e] = (o < 23) ? w3[o * 64 + d] : 0.f; }
}

// Fused 3-layer MLP for one (layer, 64-row batch tile).
// P layout: [b][d][24], d = l+1 (d=0 handled by init_param in rqs_kernel).
__global__ __launch_bounds__(256) void mlp_kernel(
    const float* __restrict__ x,
    const float* __restrict__ W1T, const float* __restrict__ b1,
    const float* __restrict__ W2T, const float* __restrict__ b2,
    const float* __restrict__ W3T, const float* __restrict__ b3,
    float* __restrict__ P)
{
    const int l   = blockIdx.y;        // 0..62
    const int b0  = blockIdx.x << 6;   // batch tile base
    const int tid = threadIdx.x;
    const int tx  = tid & 15, ty = tid >> 4;
    const int keff = l + 1;
    const int kmax = (keff + 3) & ~3;  // masked GEMM1 K extent, mult of 4

    __shared__ float Xs[64 * 68];   // x tile (stride 68 breaks bank aliasing), reused for h2
    __shared__ float Hs[64 * 68];   // h1
    __shared__ float W1s[4096];     // [k][j], stride 64
    __shared__ float W2s[4096];
    __shared__ float W3s[1536];     // [k][o], stride 24
    __shared__ float b1s[64], b2s[64], b3s[24];

    // ---- stage everything ----
    {
        const f4v* g1 = (const f4v*)(W1T + l * 4096);
        const f4v* g2 = (const f4v*)(W2T + l * 4096);
        const f4v* g3 = (const f4v*)(W3T + l * 1536);
        f4v* s1 = (f4v*)W1s; f4v* s2 = (f4v*)W2s; f4v* s3 = (f4v*)W3s;
        for (int e = tid; e < 1024; e += 256) s1[e] = g1[e];
        for (int e = tid; e < 1024; e += 256) s2[e] = g2[e];
        for (int e = tid; e < 384;  e += 256) s3[e] = g3[e];
        if (tid < 64)       b1s[tid]       = b1[l * 64 + tid];
        else if (tid < 128) b2s[tid - 64]  = b2[l * 64 + tid - 64];
        else if (tid < 152) b3s[tid - 128] = (tid < 151) ? b3[l * 23 + tid - 128] : 0.f;
        for (int e = tid; e < 4096; e += 256) {
            int r = e >> 6, d = e & 63;
            Xs[r * 68 + d] = (d < keff) ? x[(size_t)(b0 + r) * 64 + d] : 0.f;
        }
    }
    __syncthreads();

    // ---- GEMM1: h1 = tanh(Xs * W1^T + b1), K truncated to kmax ----
    float acc[4][4];
    #pragma unroll
    for (int i = 0; i < 4; i++)
        #pragma unroll
        for (int j = 0; j < 4; j++) acc[i][j] = b1s[4 * tx + j];
    for (int k = 0; k < kmax; k += 4) {
        f4v a[4], bb[4];
        #pragma unroll
        for (int i = 0; i < 4; i++)  a[i]  = *(const f4v*)&Xs[(4 * ty + i) * 68 + k];
        #pragma unroll
        for (int kk = 0; kk < 4; kk++) bb[kk] = *(const f4v*)&W1s[(k + kk) * 64 + 4 * tx];
        #pragma unroll
        for (int i = 0; i < 4; i++)
            #pragma unroll
            for (int j = 0; j < 4; j++)
                acc[i][j] += a[i][0]*bb[0][j] + a[i][1]*bb[1][j] + a[i][2]*bb[2][j] + a[i][3]*bb[3][j];
    }
    #pragma unroll
    for (int i = 0; i < 4; i++) {
        f4v hv;
        #pragma unroll
        for (int j = 0; j < 4; j++) hv[j] = fast_tanh(acc[i][j]);
        *(f4v*)&Hs[(4 * ty + i) * 68 + 4 * tx] = hv;
    }
    __syncthreads();

    // ---- GEMM2: h2 = tanh(Hs * W2^T + b2) -> into Xs ----
    #pragma unroll
    for (int i = 0; i < 4; i++)
        #pragma unroll
        for (int j = 0; j < 4; j++) acc[i][j] = b2s[4 * tx + j];
    for (int k = 0; k < 64; k += 4) {
        f4v a[4], bb[4];
        #pragma unroll
        for (int i = 0; i < 4; i++)  a[i]  = *(const f4v*)&Hs[(4 * ty + i) * 68 + k];
        #pragma unroll
        for (int kk = 0; kk < 4; kk++) bb[kk] = *(const f4v*)&W2s[(k + kk) * 64 + 4 * tx];
        #pragma unroll
        for (int i = 0; i < 4; i++)
            #pragma unroll
            for (int j = 0; j < 4; j++)
                acc[i][j] += a[i][0]*bb[0][j] + a[i][1]*bb[1][j] + a[i][2]*bb[2][j] + a[i][3]*bb[3][j];
    }
    #pragma unroll
    for (int i = 0; i < 4; i++) {
        f4v hv;
        #pragma unroll
        for (int j = 0; j < 4; j++) hv[j] = fast_tanh(acc[i][j]);
        *(f4v*)&Xs[(4 * ty + i) * 68 + 4 * tx] = hv;  // safe: nobody reads Xs during GEMM2
    }
    __syncthreads();

    // ---- GEMM3: out = h2 * W3^T + b3  (24 cols: c0=tx, c1=16+tx for tx<8) ----
    float acc3[4][2];
    const int c0 = tx, c1 = (tx < 8) ? 16 + tx : 16;
    #pragma unroll
    for (int i = 0; i < 4; i++) { acc3[i][0] = b3s[c0]; acc3[i][1] = b3s[c1]; }
    for (int k = 0; k < 64; k += 4) {
        f4v a[4];
        #pragma unroll
        for (int i = 0; i < 4; i++) a[i] = *(const f4v*)&Xs[(4 * ty + i) * 68 + k];
        #pragma unroll
        for (int kk = 0; kk < 4; kk++) {
            float w0 = W3s[(k + kk) * 24 + c0];
            float w1 = W3s[(k + kk) * 24 + c1];
            #pragma unroll
            for (int i = 0; i < 4; i++) {
                acc3[i][0] += a[i][kk] * w0;
                acc3[i][1] += a[i][kk] * w1;
            }
        }
    }
    const int dpos = l + 1;
    #pragma unroll
    for (int i = 0; i < 4; i++) {
        float* pr = P + ((size_t)(b0 + 4 * ty + i) * 64 + dpos) * 24;
        pr[c0] = acc3[i][0];
        if (tx < 8) pr[c1] = acc3[i][1];
    }
}

// Rational-quadratic spline per (b, d). One wave per batch row, lane = d.
__global__ __launch_bounds__(256) void rqs_kernel(
    const float* __restrict__ x, const float* __restrict__ init_param,
    const float* __restrict__ P, float* __restrict__ z, float* __restrict__ ld_out)
{
    const int t = threadIdx.x;
    const int d = t & 63, wv = t >> 6;
    const int b = (blockIdx.x << 2) + wv;

    float p[24];
    if (d == 0) {
        #pragma unroll
        for (int j = 0; j < 23; j++) p[j] = init_param[j];
        p[23] = 0.f;
    } else {
        const f4v* src = (const f4v*)(P + ((size_t)b * 64 + d) * 24);
        #pragma unroll
        for (int q = 0; q < 6; q++) {
            f4v v = src[q];
            p[4*q] = v[0]; p[4*q+1] = v[1]; p[4*q+2] = v[2]; p[4*q+3] = v[3];
        }
    }
    const float xv = x[(size_t)b * 64 + d];
    const bool inside = (xv >= -3.f) && (xv <= 3.f);
    const float xi = fminf(fmaxf(xv, -3.f), 3.f);

    // reference applies softmax TWICE: widths = softmax(6*softmax(p[0:8])), etc.
    float wa[8], ha[8];
    {
        float m = p[0];
        #pragma unroll
        for (int i = 1; i < 8; i++) m = fmaxf(m, p[i]);
        float s = 0.f;
        #pragma unroll
        for (int i = 0; i < 8; i++) { wa[i] = __expf(p[i] - m); s += wa[i]; }
        float inv = 6.f / s;
        #pragma unroll
        for (int i = 0; i < 8; i++) wa[i] *= inv;
        m = wa[0];
        #pragma unroll
        for (int i = 1; i < 8; i++) m = fmaxf(m, wa[i]);
        s = 0.f;
        #pragma unroll
        for (int i = 0; i < 8; i++) { wa[i] = __expf(wa[i] - m); s += wa[i]; }
        inv = 0.992f / s;  // (1 - MIN_BIN_WIDTH*K)
        #pragma unroll
        for (int i = 0; i < 8; i++) wa[i] = 1e-3f + wa[i] * inv;
    }
    {
        float m = p[8];
        #pragma unroll
        for (int i = 1; i < 8; i++) m = fmaxf(m, p[8 + i]);
        float s = 0.f;
        #pragma unroll
        for (int i = 0; i < 8; i++) { ha[i] = __expf(p[8 + i] - m); s += ha[i]; }
        float inv = 6.f / s;
        #pragma unroll
        for (int i = 0; i < 8; i++) ha[i] *= inv;
        m = ha[0];
        #pragma unroll
        for (int i = 1; i < 8; i++) m = fmaxf(m, ha[i]);
        s = 0.f;
        #pragma unroll
        for (int i = 0; i < 8; i++) { ha[i] = __expf(ha[i] - m); s += ha[i]; }
        inv = 0.992f / s;
        #pragma unroll
        for (int i = 0; i < 8; i++) ha[i] = 1e-3f + ha[i] * inv;
    }

    float cw[9], ch[9];
    cw[0] = -3.f; ch[0] = -3.f;
    {
        float cs = 0.f, hs = 0.f;
        #pragma unroll
        for (int k = 1; k < 8; k++) {
            cs += wa[k - 1]; cw[k] = 6.f * cs - 3.f;
            hs += ha[k - 1]; ch[k] = 6.f * hs - 3.f;
        }
    }
    cw[8] = 3.f; ch[8] = 3.f;

    // derivs: boundary = 1e-3 + softplus(log(exp(1-1e-3)-1)) = 1.0 exactly;
    // interior = 1e-3 + softplus(softplus(p)) (reference double-softplus)
    float dv[9];
    dv[0] = 1.0f; dv[8] = 1.0f;
    #pragma unroll
    for (int k = 1; k < 8; k++) dv[k] = 1e-3f + softplus_f(softplus_f(p[15 + k]));

    int cnt = 0;
    #pragma unroll
    for (int k = 0; k < 8; k++) cnt += (xi >= cw[k]) ? 1 : 0;
    cnt += (xi >= 3.000001f) ? 1 : 0;   // last edge + 1e-6
    const int bin = min(max(cnt - 1, 0), 7);

    float in_cw = 0.f, in_w = 1.f, in_ch = 0.f, in_h = 1.f, dk = 1.f, dk1 = 1.f;
    #pragma unroll
    for (int k = 0; k < 8; k++)
        if (k == bin) {
            in_cw = cw[k]; in_w = cw[k + 1] - cw[k];
            in_ch = ch[k]; in_h = ch[k + 1] - ch[k];
            dk = dv[k]; dk1 = dv[k + 1];
        }

    const float delta = in_h / in_w;
    const float th  = (xi - in_cw) / in_w;
    const float omt = 1.f - th;
    const float t1  = th * omt;
    const float th2 = th * th;
    const float numer = in_h * (delta * th2 + dk * t1);
    const float denom = delta + (dk + dk1 - 2.f * delta) * t1;
    const float outv  = in_ch + numer / denom;
    const float dnum  = delta * delta * (dk1 * th2 + 2.f * delta * t1 + dk * omt * omt);
    float ldv = __logf(dnum) - 2.f * __logf(denom);

    z[(size_t)b * 64 + d] = inside ? outv : xv;
    ldv = inside ? ldv : 0.f;
    #pragma unroll
    for (int off = 32; off > 0; off >>= 1) ldv += __shfl_down(ldv, off, 64);
    if (d == 0) ld_out[b] = ldv;
}

extern "C" void kernel_launch(void* const* d_in, const int* in_sizes, int n_in,
                              void* d_out, int out_size, void* d_ws, size_t ws_size,
                              hipStream_t stream)
{
    const float* x  = (const float*)d_in[0];
    const float* ip = (const float*)d_in[1];
    const float* W1 = (const float*)d_in[2];
    const float* b1 = (const float*)d_in[3];
    const float* W2 = (const float*)d_in[4];
    const float* b2 = (const float*)d_in[5];
    const float* W3 = (const float*)d_in[6];
    const float* b3 = (const float*)d_in[7];

    float* z  = (float*)d_out;                 // [B][64]
    float* ld = z + (size_t)BATCH * 64;        // [B]

    // workspace: P [B][64][24] = 100.7 MB, then transposed weights (~2.5 MB)
    float* P   = (float*)d_ws;
    float* W1T = P + (size_t)BATCH * 64 * 24;
    float* W2T = W1T + LAYERS * 4096;
    float* W3T = W2T + LAYERS * 4096;

    transpose_w<<<LAYERS, 256, 0, stream>>>(W1, W2, W3, W1T, W2T, W3T);
    mlp_kernel<<<dim3(BATCH / 64, LAYERS), 256, 0, stream>>>(x, W1T, b1, W2T, b2, W3T, b3, P);
    rqs_kernel<<<BATCH / 4, 256, 0, stream>>>(x, ip, P, z, ld);
}

// Round 2
// 252.572 us; speedup vs baseline: 3.9433x; 3.9433x over previous
//
#include <hip/hip_runtime.h>

#define BATCH 16384
#define LAYERS 63
#define BM 128
#define XS 72   // LDS row stride in bf16 elems: 144 B, 16B-aligned rows, 2-way banks max

typedef float f4 __attribute__((ext_vector_type(4)));
typedef short s8 __attribute__((ext_vector_type(8)));   // 8 x bf16

__device__ __forceinline__ float fast_tanh(float v) {
    float e = __expf(2.f * v);
    return 1.f - 2.f / (e + 1.f);
}
__device__ __forceinline__ float softplus_f(float v) {
    return fmaxf(v, 0.f) + __logf(1.f + __expf(-fabsf(v)));
}
__device__ __forceinline__ unsigned short f2bf(float f) {   // RNE fp32->bf16
    unsigned int u = __float_as_uint(f);
    u += 0x7fffu + ((u >> 16) & 1u);
    return (unsigned short)(u >> 16);
}
__device__ __forceinline__ unsigned long long pack4(float a, float b, float c, float d) {
    return (unsigned long long)((unsigned)f2bf(a) | ((unsigned)f2bf(b) << 16))
         | ((unsigned long long)((unsigned)f2bf(c) | ((unsigned)f2bf(d) << 16)) << 32);
}

// RQS spline for one (b,d): p[0..22] params, xv input. Verified vs ref in round 1.
__device__ __forceinline__ void rqs_eval(const float* p, float xv, float& zout, float& ldout) {
    const bool inside = (xv >= -3.f) && (xv <= 3.f);
    const float xi = fminf(fmaxf(xv, -3.f), 3.f);

    float wa[8], ha[8];
    {   // widths = softmax(6*softmax(p[0:8])) then affine
        float m = p[0];
        #pragma unroll
        for (int i = 1; i < 8; i++) m = fmaxf(m, p[i]);
        float s = 0.f;
        #pragma unroll
        for (int i = 0; i < 8; i++) { wa[i] = __expf(p[i] - m); s += wa[i]; }
        float inv = 6.f / s;
        #pragma unroll
        for (int i = 0; i < 8; i++) wa[i] *= inv;
        m = wa[0];
        #pragma unroll
        for (int i = 1; i < 8; i++) m = fmaxf(m, wa[i]);
        s = 0.f;
        #pragma unroll
        for (int i = 0; i < 8; i++) { wa[i] = __expf(wa[i] - m); s += wa[i]; }
        inv = 0.992f / s;
        #pragma unroll
        for (int i = 0; i < 8; i++) wa[i] = 1e-3f + wa[i] * inv;
    }
    {
        float m = p[8];
        #pragma unroll
        for (int i = 1; i < 8; i++) m = fmaxf(m, p[8 + i]);
        float s = 0.f;
        #pragma unroll
        for (int i = 0; i < 8; i++) { ha[i] = __expf(p[8 + i] - m); s += ha[i]; }
        float inv = 6.f / s;
        #pragma unroll
        for (int i = 0; i < 8; i++) ha[i] *= inv;
        m = ha[0];
        #pragma unroll
        for (int i = 1; i < 8; i++) m = fmaxf(m, ha[i]);
        s = 0.f;
        #pragma unroll
        for (int i = 0; i < 8; i++) { ha[i] = __expf(ha[i] - m); s += ha[i]; }
        inv = 0.992f / s;
        #pragma unroll
        for (int i = 0; i < 8; i++) ha[i] = 1e-3f + ha[i] * inv;
    }

    float cw[9], ch[9];
    cw[0] = -3.f; ch[0] = -3.f;
    {
        float cs = 0.f, hs = 0.f;
        #pragma unroll
        for (int k = 1; k < 8; k++) {
            cs += wa[k - 1]; cw[k] = 6.f * cs - 3.f;
            hs += ha[k - 1]; ch[k] = 6.f * hs - 3.f;
        }
    }
    cw[8] = 3.f; ch[8] = 3.f;

    float dv[9];
    dv[0] = 1.0f; dv[8] = 1.0f;   // boundary: 1e-3 + softplus(log(exp(1-1e-3)-1)) == 1.0
    #pragma unroll
    for (int k = 1; k < 8; k++) dv[k] = 1e-3f + softplus_f(softplus_f(p[15 + k]));

    int cnt = 0;
    #pragma unroll
    for (int k = 0; k < 8; k++) cnt += (xi >= cw[k]) ? 1 : 0;
    cnt += (xi >= 3.000001f) ? 1 : 0;
    const int bin = min(max(cnt - 1, 0), 7);

    float in_cw = 0.f, in_w = 1.f, in_ch = 0.f, in_h = 1.f, dk = 1.f, dk1 = 1.f;
    #pragma unroll
    for (int k = 0; k < 8; k++)
        if (k == bin) {
            in_cw = cw[k]; in_w = cw[k + 1] - cw[k];
            in_ch = ch[k]; in_h = ch[k + 1] - ch[k];
            dk = dv[k]; dk1 = dv[k + 1];
        }

    const float delta = in_h / in_w;
    const float th  = (xi - in_cw) / in_w;
    const float omt = 1.f - th;
    const float t1  = th * omt;
    const float th2 = th * th;
    const float numer = in_h * (delta * th2 + dk * t1);
    const float denom = delta + (dk + dk1 - 2.f * delta) * t1;
    const float outv  = in_ch + numer / denom;
    const float dnum  = delta * delta * (dk1 * th2 + 2.f * delta * t1 + dk * omt * omt);
    const float ldv = __logf(dnum) - 2.f * __logf(denom);

    zout  = inside ? outv : xv;
    ldout = inside ? ldv : 0.f;
}

// One block = one layer (l) x 128-row batch tile. bf16 MFMA 16x16x32.
// W layouts [j][d] row-major are already B-operand fragment layout (lane n=lane&15
// reads 8 contiguous k) -> no transpose needed. Waves are independent through all
// 3 GEMMs (each owns its 32 activation rows). Fused RQS epilogue.
__global__ __launch_bounds__(256) void mlp_rqs_kernel(
    const float* __restrict__ x,
    const float* __restrict__ W1, const float* __restrict__ b1,
    const float* __restrict__ W2, const float* __restrict__ b2,
    const float* __restrict__ W3, const float* __restrict__ b3,
    float* __restrict__ zT, float* __restrict__ ldT)
{
    const int l    = blockIdx.y, keff = l + 1;   // layer; dpos = keff
    const int b0   = blockIdx.x * BM;
    const int tid  = threadIdx.x;

    __shared__ __align__(16) unsigned short Xs[BM * XS];   // x tile bf16; reused for h2
    __shared__ __align__(16) unsigned short Hs[BM * XS];   // h1 bf16
    __shared__ __align__(16) float W12f[4608];             // W1s|W2s bf16; later Ps[BM][24] f32
    __shared__ __align__(16) unsigned short W3s[32 * XS];  // W3 padded to 32 rows
    __shared__ float b1s[64], b2s[64], b3s[32];

    unsigned short* W12s = (unsigned short*)W12f;

    // ---- stage: X (zero d>=keff), W1, W2, W3(pad), biases ----
    for (int e = tid; e < BM * 16; e += 256) {             // 2048 float4 groups
        int r = e >> 4, c4 = (e & 15) * 4;
        f4 v = *(const f4*)&x[(size_t)(b0 + r) * 64 + c4];
        float v0 = (c4 + 0 < keff) ? v[0] : 0.f;
        float v1 = (c4 + 1 < keff) ? v[1] : 0.f;
        float v2 = (c4 + 2 < keff) ? v[2] : 0.f;
        float v3 = (c4 + 3 < keff) ? v[3] : 0.f;
        *(unsigned long long*)&Xs[r * XS + c4] = pack4(v0, v1, v2, v3);
    }
    {
        const float* w1g = W1 + l * 4096;
        const float* w2g = W2 + l * 4096;
        for (int e = tid; e < 2048; e += 256) {
            int m = e >> 10, i = e & 1023;
            int r = i >> 4, c4 = (i & 15) * 4;
            f4 v = *(const f4*)&((m ? w2g : w1g)[r * 64 + c4]);
            *(unsigned long long*)&W12s[m * 4608 + r * XS + c4] = pack4(v[0], v[1], v[2], v[3]);
        }
        const float* w3g = W3 + l * (23 * 64);
        for (int e = tid; e < 512; e += 256) {
            int r = e >> 4, c4 = (e & 15) * 4;
            unsigned long long w = 0ull;
            if (r < 23) {
                f4 v = *(const f4*)&w3g[r * 64 + c4];
                w = pack4(v[0], v[1], v[2], v[3]);
            }
            *(unsigned long long*)&W3s[r * XS + c4] = w;
        }
    }
    if (tid < 64)        b1s[tid]        = b1[l * 64 + tid];
    else if (tid < 128)  b2s[tid - 64]   = b2[l * 64 + tid - 64];
    else if (tid < 160)  b3s[tid - 128]  = (tid - 128 < 23) ? b3[l * 23 + tid - 128] : 0.f;
    __syncthreads();

    const int ln = tid & 63, wv = tid >> 6;
    const int c = ln & 15, q = ln >> 4;        // A/B frag: row/col = c, k-quarter = q
    const int mbase = wv * 32;
    const int k0q = q * 8;

    // ---- GEMM1: H1 = tanh(X * W1^T + b1), K truncated by tril mask ----
    {
        f4 acc[2][4];
        #pragma unroll
        for (int mt = 0; mt < 2; mt++)
            #pragma unroll
            for (int nt = 0; nt < 4; nt++) {
                float bv = b1s[nt * 16 + c];
                acc[mt][nt] = f4{bv, bv, bv, bv};
            }
        const int ks1 = (keff + 31) >> 5;
        for (int ks = 0; ks < ks1; ks++) {
            int ko = ks * 32 + k0q;
            s8 a0 = *(const s8*)&Xs[(mbase + c) * XS + ko];
            s8 a1 = *(const s8*)&Xs[(mbase + 16 + c) * XS + ko];
            #pragma unroll
            for (int nt = 0; nt < 4; nt++) {
                s8 bb = *(const s8*)&W12s[(nt * 16 + c) * XS + ko];
                acc[0][nt] = __builtin_amdgcn_mfma_f32_16x16x32_bf16(a0, bb, acc[0][nt], 0, 0, 0);
                acc[1][nt] = __builtin_amdgcn_mfma_f32_16x16x32_bf16(a1, bb, acc[1][nt], 0, 0, 0);
            }
        }
        #pragma unroll
        for (int mt = 0; mt < 2; mt++)
            #pragma unroll
            for (int nt = 0; nt < 4; nt++)
                #pragma unroll
                for (int r = 0; r < 4; r++)
                    Hs[(mbase + mt * 16 + q * 4 + r) * XS + nt * 16 + c] =
                        f2bf(fast_tanh(acc[mt][nt][r]));
    }

    // ---- GEMM2: H2 = tanh(H1 * W2^T + b2) -> back into Xs (own rows only) ----
    {
        f4 acc[2][4];
        #pragma unroll
        for (int mt = 0; mt < 2; mt++)
            #pragma unroll
            for (int nt = 0; nt < 4; nt++) {
                float bv = b2s[nt * 16 + c];
                acc[mt][nt] = f4{bv, bv, bv, bv};
            }
        #pragma unroll
        for (int ks = 0; ks < 2; ks++) {
            int ko = ks * 32 + k0q;
            s8 a0 = *(const s8*)&Hs[(mbase + c) * XS + ko];
            s8 a1 = *(const s8*)&Hs[(mbase + 16 + c) * XS + ko];
            #pragma unroll
            for (int nt = 0; nt < 4; nt++) {
                s8 bb = *(const s8*)&W12s[4608 + (nt * 16 + c) * XS + ko];
                acc[0][nt] = __builtin_amdgcn_mfma_f32_16x16x32_bf16(a0, bb, acc[0][nt], 0, 0, 0);
                acc[1][nt] = __builtin_amdgcn_mfma_f32_16x16x32_bf16(a1, bb, acc[1][nt], 0, 0, 0);
            }
        }
        #pragma unroll
        for (int mt = 0; mt < 2; mt++)
            #pragma unroll
            for (int nt = 0; nt < 4; nt++)
                #pragma unroll
                for (int r = 0; r < 4; r++)
                    Xs[(mbase + mt * 16 + q * 4 + r) * XS + nt * 16 + c] =
                        f2bf(fast_tanh(acc[mt][nt][r]));
    }

    // ---- GEMM3: OUT = H2 * W3^T + b3 (23 cols, padded to 32) ----
    f4 acc3[2][2];
    #pragma unroll
    for (int mt = 0; mt < 2; mt++)
        #pragma unroll
        for (int nt = 0; nt < 2; nt++) {
            float bv = b3s[nt * 16 + c];
            acc3[mt][nt] = f4{bv, bv, bv, bv};
        }
    #pragma unroll
    for (int ks = 0; ks < 2; ks++) {
        int ko = ks * 32 + k0q;
        s8 a0 = *(const s8*)&Xs[(mbase + c) * XS + ko];
        s8 a1 = *(const s8*)&Xs[(mbase + 16 + c) * XS + ko];
        #pragma unroll
        for (int nt = 0; nt < 2; nt++) {
            s8 bb = *(const s8*)&W3s[(nt * 16 + c) * XS + ko];
            acc3[0][nt] = __builtin_amdgcn_mfma_f32_16x16x32_bf16(a0, bb, acc3[0][nt], 0, 0, 0);
            acc3[1][nt] = __builtin_amdgcn_mfma_f32_16x16x32_bf16(a1, bb, acc3[1][nt], 0, 0, 0);
        }
    }
    __syncthreads();   // all waves done reading W12s -> safe to reuse as Ps

    float* Ps = W12f;  // [BM][24]
    #pragma unroll
    for (int mt = 0; mt < 2; mt++)
        #pragma unroll
        for (int nt = 0; nt < 2; nt++) {
            int o = nt * 16 + c;
            if (o < 23) {
                #pragma unroll
                for (int r = 0; r < 4; r++)
                    Ps[(mbase + mt * 16 + q * 4 + r) * 24 + o] = acc3[mt][nt][r];
            }
        }
    __syncthreads();

    // ---- fused RQS: one thread per batch row; write transposed for coalescing ----
    if (tid < BM) {
        const int r = tid;
        float p[23];
        #pragma unroll
        for (int j = 0; j < 23; j++) p[j] = Ps[r * 24 + j];
        const float xv = x[(size_t)(b0 + r) * 64 + keff];
        float zv, ldv;
        rqs_eval(p, xv, zv, ldv);
        zT[(size_t)keff * BATCH + b0 + r]  = zv;
        ldT[(size_t)keff * BATCH + b0 + r] = ldv;
    }
}

// Transpose zT -> z, reduce ldT over d, handle d=0 (init_param spline).
__global__ __launch_bounds__(256) void finish_kernel(
    const float* __restrict__ x, const float* __restrict__ init_param,
    const float* __restrict__ zT, const float* __restrict__ ldT,
    float* __restrict__ z, float* __restrict__ ld_out)
{
    __shared__ float zt[64 * 65], lt[64 * 65];   // [d][b-tile], stride 65 -> conflict-free
    const int b0 = blockIdx.x * 64, tid = threadIdx.x;

    for (int e = tid; e < 64 * 16; e += 256) {
        int d = e >> 4, c4 = (e & 15) * 4;
        if (d >= 1) {
            f4 v = *(const f4*)&zT[(size_t)d * BATCH + b0 + c4];
            f4 w = *(const f4*)&ldT[(size_t)d * BATCH + b0 + c4];
            #pragma unroll
            for (int j = 0; j < 4; j++) { zt[d * 65 + c4 + j] = v[j]; lt[d * 65 + c4 + j] = w[j]; }
        }
    }
    if (tid < 64) {   // d = 0: params are init_param for every row
        float p[23];
        #pragma unroll
        for (int j = 0; j < 23; j++) p[j] = init_param[j];
        const float xv = x[(size_t)(b0 + tid) * 64];
        float zv, ldv;
        rqs_eval(p, xv, zv, ldv);
        zt[tid] = zv; lt[tid] = ldv;
    }
    __syncthreads();

    for (int e = tid; e < 4096; e += 256) {      // z[b][d] coalesced over d
        int r = e >> 6, d = e & 63;
        z[(size_t)(b0 + r) * 64 + d] = zt[d * 65 + r];
    }
    if (tid < 64) {
        float s = 0.f;
        for (int d = 0; d < 64; d++) s += lt[d * 65 + tid];
        ld_out[b0 + tid] = s;
    }
}

extern "C" void kernel_launch(void* const* d_in, const int* in_sizes, int n_in,
                              void* d_out, int out_size, void* d_ws, size_t ws_size,
                              hipStream_t stream)
{
    const float* x  = (const float*)d_in[0];
    const float* ip = (const float*)d_in[1];
    const float* W1 = (const float*)d_in[2];
    const float* b1 = (const float*)d_in[3];
    const float* W2 = (const float*)d_in[4];
    const float* b2 = (const float*)d_in[5];
    const float* W3 = (const float*)d_in[6];
    const float* b3 = (const float*)d_in[7];

    float* z  = (float*)d_out;                  // [B][64]
    float* ld = z + (size_t)BATCH * 64;         // [B]

    float* zT  = (float*)d_ws;                  // [64][B] (row 0 unused)
    float* ldT = zT + (size_t)64 * BATCH;       // [64][B]

    mlp_rqs_kernel<<<dim3(BATCH / BM, LAYERS), 256, 0, stream>>>(
        x, W1, b1, W2, b2, W3, b3, zT, ldT);
    finish_kernel<<<BATCH / 64, 256, 0, stream>>>(x, ip, zT, ldT, z, ld);
}

// Round 3
// 188.147 us; speedup vs baseline: 5.2935x; 1.3424x over previous
//
#include <hip/hip_runtime.h>

#define BATCH 16384
#define LAYERS 63
#define BM 128
#define XS 72          // Hs row stride in bf16: 144 B -> bank rotation, b128 reads at floor
#define BLOB_BYTES 21504   // per-layer: W12 16384 | W3 4096 | b1 256 | b2 256 | b3 128 | pad 384

typedef float f4 __attribute__((ext_vector_type(4)));
typedef short s8 __attribute__((ext_vector_type(8)));          // 8 x bf16
typedef unsigned int u4 __attribute__((ext_vector_type(4)));   // same 16 B as s8

__device__ __forceinline__ float fast_tanh(float v) {
    float e = __expf(2.f * v);
    return 1.f - 2.f / (e + 1.f);
}
__device__ __forceinline__ float softplus_f(float v) {
    return fmaxf(v, 0.f) + __logf(1.f + __expf(-fabsf(v)));
}
__device__ __forceinline__ unsigned short f2bf(float f) {   // RNE fp32->bf16
    unsigned int u = __float_as_uint(f);
    u += 0x7fffu + ((u >> 16) & 1u);
    return (unsigned short)(u >> 16);
}
__device__ __forceinline__ unsigned long long pack4(float a, float b, float c, float d) {
    return (unsigned long long)((unsigned)f2bf(a) | ((unsigned)f2bf(b) << 16))
         | ((unsigned long long)((unsigned)f2bf(c) | ((unsigned)f2bf(d) << 16)) << 32);
}

// RQS spline for one (b,d). Verified vs reference in rounds 1-2.
__device__ __forceinline__ void rqs_eval(const float* p, float xv, float& zout, float& ldout) {
    const bool inside = (xv >= -3.f) && (xv <= 3.f);
    const float xi = fminf(fmaxf(xv, -3.f), 3.f);

    float wa[8], ha[8];
    {   // widths = softmax(6*softmax(p[0:8])) then affine (reference double-softmax)
        float m = p[0];
        #pragma unroll
        for (int i = 1; i < 8; i++) m = fmaxf(m, p[i]);
        float s = 0.f;
        #pragma unroll
        for (int i = 0; i < 8; i++) { wa[i] = __expf(p[i] - m); s += wa[i]; }
        float inv = 6.f / s;
        #pragma unroll
        for (int i = 0; i < 8; i++) wa[i] *= inv;
        m = wa[0];
        #pragma unroll
        for (int i = 1; i < 8; i++) m = fmaxf(m, wa[i]);
        s = 0.f;
        #pragma unroll
        for (int i = 0; i < 8; i++) { wa[i] = __expf(wa[i] - m); s += wa[i]; }
        inv = 0.992f / s;
        #pragma unroll
        for (int i = 0; i < 8; i++) wa[i] = 1e-3f + wa[i] * inv;
    }
    {
        float m = p[8];
        #pragma unroll
        for (int i = 1; i < 8; i++) m = fmaxf(m, p[8 + i]);
        float s = 0.f;
        #pragma unroll
        for (int i = 0; i < 8; i++) { ha[i] = __expf(p[8 + i] - m); s += ha[i]; }
        float inv = 6.f / s;
        #pragma unroll
        for (int i = 0; i < 8; i++) ha[i] *= inv;
        m = ha[0];
        #pragma unroll
        for (int i = 1; i < 8; i++) m = fmaxf(m, ha[i]);
        s = 0.f;
        #pragma unroll
        for (int i = 0; i < 8; i++) { ha[i] = __expf(ha[i] - m); s += ha[i]; }
        inv = 0.992f / s;
        #pragma unroll
        for (int i = 0; i < 8; i++) ha[i] = 1e-3f + ha[i] * inv;
    }

    float cw[9], ch[9];
    cw[0] = -3.f; ch[0] = -3.f;
    {
        float cs = 0.f, hs = 0.f;
        #pragma unroll
        for (int k = 1; k < 8; k++) {
            cs += wa[k - 1]; cw[k] = 6.f * cs - 3.f;
            hs += ha[k - 1]; ch[k] = 6.f * hs - 3.f;
        }
    }
    cw[8] = 3.f; ch[8] = 3.f;

    float dv[9];
    dv[0] = 1.0f; dv[8] = 1.0f;   // boundary: 1e-3 + softplus(log(exp(1-1e-3)-1)) == 1.0
    #pragma unroll
    for (int k = 1; k < 8; k++) dv[k] = 1e-3f + softplus_f(softplus_f(p[15 + k]));

    int cnt = 0;
    #pragma unroll
    for (int k = 0; k < 8; k++) cnt += (xi >= cw[k]) ? 1 : 0;
    cnt += (xi >= 3.000001f) ? 1 : 0;
    const int bin = min(max(cnt - 1, 0), 7);

    float in_cw = 0.f, in_w = 1.f, in_ch = 0.f, in_h = 1.f, dk = 1.f, dk1 = 1.f;
    #pragma unroll
    for (int k = 0; k < 8; k++)
        if (k == bin) {
            in_cw = cw[k]; in_w = cw[k + 1] - cw[k];
            in_ch = ch[k]; in_h = ch[k + 1] - ch[k];
            dk = dv[k]; dk1 = dv[k + 1];
        }

    const float delta = in_h / in_w;
    const float th  = (xi - in_cw) / in_w;
    const float omt = 1.f - th;
    const float t1  = th * omt;
    const float th2 = th * th;
    const float numer = in_h * (delta * th2 + dk * t1);
    const float denom = delta + (dk + dk1 - 2.f * delta) * t1;
    const float outv  = in_ch + numer / denom;
    const float dnum  = delta * delta * (dk1 * th2 + 2.f * delta * t1 + dk * omt * omt);
    const float ldv = __logf(dnum) - 2.f * __logf(denom);

    zout  = inside ? outv : xv;
    ldout = inside ? ldv : 0.f;
}

// Prep: x -> bf16; weights -> per-layer bf16 blob in LDS-image order with XOR-8
// 16B-block swizzle (so global_load_lds staging + swizzled ds_read_b128 are both
// at bank floor). Biases stay f32, appended.
__global__ __launch_bounds__(256) void prep_kernel(
    const float* __restrict__ x,
    const float* __restrict__ W1, const float* __restrict__ W2, const float* __restrict__ W3,
    const float* __restrict__ b1, const float* __restrict__ b2, const float* __restrict__ b3,
    unsigned short* __restrict__ x_bf, unsigned char* __restrict__ blobG)
{
    const int tid = threadIdx.x;
    if (blockIdx.x < 1024) {                    // x convert: 262144 quads
        size_t idx = (size_t)blockIdx.x * 256 + tid;
        f4 v = *(const f4*)&x[idx * 4];
        *(unsigned long long*)&x_bf[idx * 4] = pack4(v[0], v[1], v[2], v[3]);
        return;
    }
    const int l = blockIdx.x - 1024;
    unsigned char* gb = blobG + (size_t)l * BLOB_BYTES;
    for (int e = tid; e < 1024; e += 256) {     // W1|W2: (m, row r, block j)
        int m = e >> 9, r = (e >> 3) & 63, j = e & 7;
        const float* src = (m ? W2 : W1) + (size_t)l * 4096 + r * 64 + j * 8;
        unsigned long long lo = pack4(src[0], src[1], src[2], src[3]);
        unsigned long long hi = pack4(src[4], src[5], src[6], src[7]);
        unsigned long long* dst = (unsigned long long*)(gb + m * 8192 + r * 128 + ((j ^ (r & 7)) << 4));
        dst[0] = lo; dst[1] = hi;
    }
    {                                           // W3 padded to 32 rows
        int e = tid;
        if (e < 256) {
            int r = e >> 3, j = e & 7;
            unsigned long long lo = 0ull, hi = 0ull;
            if (r < 23) {
                const float* src = W3 + (size_t)l * 1472 + r * 64 + j * 8;
                lo = pack4(src[0], src[1], src[2], src[3]);
                hi = pack4(src[4], src[5], src[6], src[7]);
            }
            unsigned long long* dst = (unsigned long long*)(gb + 16384 + r * 128 + ((j ^ (r & 7)) << 4));
            dst[0] = lo; dst[1] = hi;
        }
    }
    if (tid < 64)        *(float*)(gb + 20480 + tid * 4)         = b1[l * 64 + tid];
    else if (tid < 128)  *(float*)(gb + 20736 + (tid - 64) * 4)  = b2[l * 64 + tid - 64];
    else if (tid < 160)  *(float*)(gb + 20992 + (tid - 128) * 4) = (tid - 128 < 23) ? b3[l * 23 + tid - 128] : 0.f;
    else                 { int e = tid - 160; if (e < 96) *(float*)(gb + 21120 + e * 4) = 0.f; }
}

// One block = one layer x 128 rows. Weights via global_load_lds DMA; X A-frags
// straight from global bf16 (tril mask applied in-register on the boundary K
// chunk). Single activation buffer (wave-private rows -> no GEMM barriers).
__global__ __launch_bounds__(256, 4) void mlp_rqs_kernel(
    const float* __restrict__ x, const unsigned short* __restrict__ x_bf,
    const unsigned char* __restrict__ blobG,
    float* __restrict__ zT, float* __restrict__ ldT)
{
    const int l = blockIdx.y, keff = l + 1;
    const int b0 = blockIdx.x * BM;
    const int tid = threadIdx.x;
    const int ln = tid & 63, wv = tid >> 6;
    const int c = ln & 15, q = ln >> 4;
    const int mbase = wv * 32;

    __shared__ __align__(16) unsigned char blob[BLOB_BYTES];
    __shared__ __align__(16) unsigned short Hs[BM * XS];

    unsigned short* W12s = (unsigned short*)blob;              // elems; row r at r*64
    unsigned short* W3s  = (unsigned short*)(blob + 16384);
    const float* b1s = (const float*)(blob + 20480);
    const float* b2s = (const float*)(blob + 20736);
    const float* b3s = (const float*)(blob + 20992);

    // ---- async DMA: whole layer blob, 21 x 1KB chunks over 4 waves ----
    {
        const unsigned char* g = blobG + (size_t)l * BLOB_BYTES + ln * 16;
        for (int t = wv; t < 21; t += 4)
            __builtin_amdgcn_global_load_lds(
                (const __attribute__((address_space(1))) void*)(g + t * 1024),
                (__attribute__((address_space(3))) void*)(blob + t * 1024), 16, 0, 0);
    }

    // ---- A-frags from global (independent of DMA): rows mbase+c, mbase+16+c ----
    const int ks1 = (keff + 31) >> 5;     // 1 or 2
    u4 a0f, a1f, a0l, a1l;
    {
        const unsigned short* xr = x_bf + (size_t)(b0 + mbase + c) * 64 + q * 8;
        a0f = *(const u4*)xr;  a1f = *(const u4*)(xr + 16 * 64);
        if (ks1 == 2) { a0l = *(const u4*)(xr + 32); a1l = *(const u4*)(xr + 16 * 64 + 32); }
        const int n = keff - ((ks1 - 1) * 32 + q * 8);   // valid elems in boundary chunk
        unsigned mk[4];
        #pragma unroll
        for (int i = 0; i < 4; i++) {
            int m = n - 2 * i;
            mk[i] = (m >= 2) ? 0xFFFFFFFFu : ((m == 1) ? 0xFFFFu : 0u);
        }
        if (ks1 == 2) {
            #pragma unroll
            for (int i = 0; i < 4; i++) { a0l[i] &= mk[i]; a1l[i] &= mk[i]; }
        } else {
            #pragma unroll
            for (int i = 0; i < 4; i++) { a0f[i] &= mk[i]; a1f[i] &= mk[i]; }
        }
    }
    __syncthreads();   // weights + biases resident

    const int c7 = c & 7;

    // ---- GEMM1: H1 = tanh(X W1^T + b1), K truncated by tril ----
    {
        f4 acc[2][4];
        #pragma unroll
        for (int nt = 0; nt < 4; nt++) {
            float bv = b1s[nt * 16 + c];
            acc[0][nt] = f4{bv, bv, bv, bv};
            acc[1][nt] = f4{bv, bv, bv, bv};
        }
        {
            const int s0 = (q ^ c7) * 8;
            s8 A0 = __builtin_bit_cast(s8, a0f), A1 = __builtin_bit_cast(s8, a1f);
            #pragma unroll
            for (int nt = 0; nt < 4; nt++) {
                s8 bb = *(const s8*)&W12s[(nt * 16 + c) * 64 + s0];
                acc[0][nt] = __builtin_amdgcn_mfma_f32_16x16x32_bf16(A0, bb, acc[0][nt], 0, 0, 0);
                acc[1][nt] = __builtin_amdgcn_mfma_f32_16x16x32_bf16(A1, bb, acc[1][nt], 0, 0, 0);
            }
        }
        if (ks1 == 2) {
            const int s1 = ((4 + q) ^ c7) * 8;
            s8 A0 = __builtin_bit_cast(s8, a0l), A1 = __builtin_bit_cast(s8, a1l);
            #pragma unroll
            for (int nt = 0; nt < 4; nt++) {
                s8 bb = *(const s8*)&W12s[(nt * 16 + c) * 64 + s1];
                acc[0][nt] = __builtin_amdgcn_mfma_f32_16x16x32_bf16(A0, bb, acc[0][nt], 0, 0, 0);
                acc[1][nt] = __builtin_amdgcn_mfma_f32_16x16x32_bf16(A1, bb, acc[1][nt], 0, 0, 0);
            }
        }
        #pragma unroll
        for (int mt = 0; mt < 2; mt++)
            #pragma unroll
            for (int nt = 0; nt < 4; nt++)
                #pragma unroll
                for (int r = 0; r < 4; r++)
                    Hs[(mbase + mt * 16 + q * 4 + r) * XS + nt * 16 + c] =
                        f2bf(fast_tanh(acc[mt][nt][r]));
    }

    // ---- GEMM2: H2 = tanh(H1 W2^T + b2), overwrite own Hs rows (no barrier) ----
    {
        f4 acc[2][4];
        #pragma unroll
        for (int nt = 0; nt < 4; nt++) {
            float bv = b2s[nt * 16 + c];
            acc[0][nt] = f4{bv, bv, bv, bv};
            acc[1][nt] = f4{bv, bv, bv, bv};
        }
        #pragma unroll
        for (int ks = 0; ks < 2; ks++) {
            s8 h0 = *(const s8*)&Hs[(mbase + c) * XS + ks * 32 + q * 8];
            s8 h1 = *(const s8*)&Hs[(mbase + 16 + c) * XS + ks * 32 + q * 8];
            const int sb = ((ks * 4 + q) ^ c7) * 8;
            #pragma unroll
            for (int nt = 0; nt < 4; nt++) {
                s8 bb = *(const s8*)&W12s[4096 + (nt * 16 + c) * 64 + sb];
                acc[0][nt] = __builtin_amdgcn_mfma_f32_16x16x32_bf16(h0, bb, acc[0][nt], 0, 0, 0);
                acc[1][nt] = __builtin_amdgcn_mfma_f32_16x16x32_bf16(h1, bb, acc[1][nt], 0, 0, 0);
            }
        }
        #pragma unroll
        for (int mt = 0; mt < 2; mt++)
            #pragma unroll
            for (int nt = 0; nt < 4; nt++)
                #pragma unroll
                for (int r = 0; r < 4; r++)
                    Hs[(mbase + mt * 16 + q * 4 + r) * XS + nt * 16 + c] =
                        f2bf(fast_tanh(acc[mt][nt][r]));
    }

    // ---- GEMM3: OUT = H2 W3^T + b3 (23 cols padded to 32) ----
    f4 acc3[2][2];
    #pragma unroll
    for (int nt = 0; nt < 2; nt++) {
        float bv = b3s[nt * 16 + c];
        acc3[0][nt] = f4{bv, bv, bv, bv};
        acc3[1][nt] = f4{bv, bv, bv, bv};
    }
    #pragma unroll
    for (int ks = 0; ks < 2; ks++) {
        s8 h0 = *(const s8*)&Hs[(mbase + c) * XS + ks * 32 + q * 8];
        s8 h1 = *(const s8*)&Hs[(mbase + 16 + c) * XS + ks * 32 + q * 8];
        const int sb = ((ks * 4 + q) ^ c7) * 8;
        #pragma unroll
        for (int nt = 0; nt < 2; nt++) {
            s8 bb = *(const s8*)&W3s[(nt * 16 + c) * 64 + sb];
            acc3[0][nt] = __builtin_amdgcn_mfma_f32_16x16x32_bf16(h0, bb, acc3[0][nt], 0, 0, 0);
            acc3[1][nt] = __builtin_amdgcn_mfma_f32_16x16x32_bf16(h1, bb, acc3[1][nt], 0, 0, 0);
        }
    }
    __syncthreads();   // all waves done reading W12s -> reuse as Ps

    float* Ps = (float*)blob;   // [BM][24] = 12288 B < 16384 B
    #pragma unroll
    for (int mt = 0; mt < 2; mt++)
        #pragma unroll
        for (int nt = 0; nt < 2; nt++) {
            int o = nt * 16 + c;
            if (o < 23) {
                #pragma unroll
                for (int r = 0; r < 4; r++)
                    Ps[(mbase + mt * 16 + q * 4 + r) * 24 + o] = acc3[mt][nt][r];
            }
        }
    __syncthreads();

    // ---- fused RQS epilogue: one thread per row, transposed coalesced store ----
    if (tid < BM) {
        float p[23];
        #pragma unroll
        for (int j = 0; j < 23; j++) p[j] = Ps[tid * 24 + j];
        const float xv = x[(size_t)(b0 + tid) * 64 + keff];
        float zv, ldv;
        rqs_eval(p, xv, zv, ldv);
        zT[(size_t)keff * BATCH + b0 + tid]  = zv;
        ldT[(size_t)keff * BATCH + b0 + tid] = ldv;
    }
}

// Transpose zT -> z, reduce ldT over d (coalesced, register-accumulated), d=0 spline.
__global__ __launch_bounds__(256) void finish_kernel(
    const float* __restrict__ x, const float* __restrict__ init_param,
    const float* __restrict__ zT, const float* __restrict__ ldT,
    float* __restrict__ z, float* __restrict__ ld_out)
{
    __shared__ float zt[64 * 65];
    __shared__ float z0buf[128];
    __shared__ float red[128];
    const int b0 = blockIdx.x * 128, tid = threadIdx.x;
    const int bb = tid & 127, half = tid >> 7;

    float ld0 = 0.f;
    if (half == 0) {   // d = 0: params are init_param for every row
        float p[23];
        #pragma unroll
        for (int j = 0; j < 23; j++) p[j] = init_param[j];
        const float xv = x[(size_t)(b0 + bb) * 64];
        float zv, lv;
        rqs_eval(p, xv, zv, lv);
        z0buf[bb] = zv; ld0 = lv;
    }
    float s = 0.f;
    {
        const int dlo = half ? 32 : 1, dhi = half ? 64 : 32;
        for (int d = dlo; d < dhi; ++d)
            s += ldT[(size_t)d * BATCH + b0 + bb];
    }
    if (half) red[bb] = s;
    __syncthreads();
    if (!half) ld_out[b0 + bb] = s + red[bb] + ld0;

    #pragma unroll
    for (int st = 0; st < 2; ++st) {
        __syncthreads();
        const int sb = b0 + st * 64;
        for (int e = tid; e < 63 * 16; e += 256) {
            int d = (e >> 4) + 1, c4 = (e & 15) * 4;
            f4 v = *(const f4*)&zT[(size_t)d * BATCH + sb + c4];
            #pragma unroll
            for (int j = 0; j < 4; j++) zt[d * 65 + c4 + j] = v[j];
        }
        if (tid < 64) zt[tid] = z0buf[st * 64 + tid];
        __syncthreads();
        for (int e = tid; e < 1024; e += 256) {       // 64 rows x 16 f4 groups
            int r = e >> 4, d4 = (e & 15) * 4;
            f4 w;
            #pragma unroll
            for (int j = 0; j < 4; j++) w[j] = zt[(d4 + j) * 65 + r];
            *(f4*)&z[(size_t)(sb + r) * 64 + d4] = w;
        }
    }
}

extern "C" void kernel_launch(void* const* d_in, const int* in_sizes, int n_in,
                              void* d_out, int out_size, void* d_ws, size_t ws_size,
                              hipStream_t stream)
{
    const float* x  = (const float*)d_in[0];
    const float* ip = (const float*)d_in[1];
    const float* W1 = (const float*)d_in[2];
    const float* b1 = (const float*)d_in[3];
    const float* W2 = (const float*)d_in[4];
    const float* b2 = (const float*)d_in[5];
    const float* W3 = (const float*)d_in[6];
    const float* b3 = (const float*)d_in[7];

    float* z  = (float*)d_out;                  // [B][64]
    float* ld = z + (size_t)BATCH * 64;         // [B]

    float* zT  = (float*)d_ws;                               // [64][B]
    float* ldT = zT + (size_t)64 * BATCH;                    // [64][B]
    unsigned short* x_bf = (unsigned short*)(ldT + (size_t)64 * BATCH);   // [B][64] bf16
    unsigned char*  blobG = (unsigned char*)(x_bf + (size_t)BATCH * 64);  // 63 * 21504 B

    prep_kernel<<<1024 + LAYERS, 256, 0, stream>>>(x, W1, W2, W3, b1, b2, b3, x_bf, blobG);
    mlp_rqs_kernel<<<dim3(BATCH / BM, LAYERS), 256, 0, stream>>>(x, x_bf, blobG, zT, ldT);
    finish_kernel<<<BATCH / 128, 256, 0, stream>>>(x, ip, zT, ldT, z, ld);
}